// Round 7
// baseline (384.567 us; speedup 1.0000x reference)
//
#include <hip/hip_runtime.h>

#define HIDDEN 2048
#define NH 16
#define NKV 4
#define HD 128
#define Bb 2
#define Ss 2048
#define TOK 4096           // Bb*Ss
#define KVD 512            // NKV*HD
#define LOG2E 1.4426950408889634f
#define QSCALE (0.08838834764831845f * 1.4426950408889634f)   // log2e/sqrt(128)
#define DEFER 11.54f       // 8 nats in log2 units

typedef short short8 __attribute__((ext_vector_type(8)));
typedef float f32x4 __attribute__((ext_vector_type(4)));

#define AS1 __attribute__((address_space(1)))
#define AS3 __attribute__((address_space(3)))

__device__ __forceinline__ float exp2fast(float x){ return __builtin_amdgcn_exp2f(x); }

__device__ __forceinline__ float bf2f(unsigned short u){
  union { unsigned int i; float f; } x; x.i = ((unsigned int)u) << 16; return x.f;
}
__device__ __forceinline__ unsigned short f2bf(float f){
  union { float f; unsigned int i; } x; x.f = f;
  unsigned int r = x.i + 0x7FFFu + ((x.i >> 16) & 1u);   // RNE
  return (unsigned short)(r >> 16);
}
__device__ __forceinline__ void gld_lds16(const void* g, void* l){
  __builtin_amdgcn_global_load_lds((const AS1 void*)g, (AS3 void*)l, 16, 0, 0);
}

// ---------------- fused fp32 -> bf16 conversion of all 5 tensors ----------------
#define R0 2097152   // hs  f4 count
#define R1 3145728   // + qw
#define R2 3407872   // + kw
#define R3 3670016   // + vw
#define R4 4718592   // + ow (total)
__global__ void cvt_all(const float* __restrict__ s0, const float* __restrict__ s1,
                        const float* __restrict__ s2, const float* __restrict__ s3,
                        const float* __restrict__ s4, unsigned short* __restrict__ dst){
  int i = blockIdx.x * 256 + threadIdx.x;     // float4 index, grid exact
  const float* src; int off;
  if      (i < R0){ src = s0; off = 0;  }
  else if (i < R1){ src = s1; off = R0; }
  else if (i < R2){ src = s2; off = R1; }
  else if (i < R3){ src = s3; off = R2; }
  else            { src = s4; off = R3; }
  float4 v = reinterpret_cast<const float4*>(src)[i - off];
  ushort4 o;
  o.x = f2bf(v.x); o.y = f2bf(v.y); o.z = f2bf(v.z); o.w = f2bf(v.w);
  reinterpret_cast<ushort4*>(dst)[i] = o;
}

// ---------------- NT GEMM: C[M,N] = A[M,K] * B[N,K]^T (+bias) ----------------
// vT non-null: cols >= 512 are written TRANSPOSED to vT[(col-512)*TOK + row] (V^T layout).
__global__ __launch_bounds__(256) void gemm_nt(
    const unsigned short* __restrict__ A,
    const unsigned short* __restrict__ Bw,
    const float* __restrict__ bias,        // may be null
    const float* __restrict__ bias2,       // if non-null: used for col >= 512
    unsigned short* __restrict__ Cb,       // bf16 out (if Cf==null)
    float* __restrict__ Cf,                // f32 out (if non-null)
    unsigned short* __restrict__ vT,       // transposed bf16 out for col>=512
    int M, int N, int K, int ldc)
{
  __shared__ unsigned short Alds[128*32];
  __shared__ unsigned short Blds[128*32];
  const int tid  = threadIdx.x;
  const int lane = tid & 63;
  const int wr = (tid >> 7) & 1;
  const int wc = (tid >> 6) & 1;
  const int row0 = blockIdx.x * 128;
  const int col0 = blockIdx.y * 128;

  const f32x4 vzero = {0.f, 0.f, 0.f, 0.f};
  f32x4 acc[4][4];
#pragma unroll
  for (int m = 0; m < 4; m++)
#pragma unroll
    for (int n = 0; n < 4; n++) acc[m][n] = vzero;

  const int c0 = tid, c1 = tid + 256;
  const int ra0 = c0 >> 2, ka0 = (c0 & 3) * 8;
  const int ra1 = c1 >> 2, ka1 = (c1 & 3) * 8;

  const int fr  = lane & 15;
  const int fk8 = (lane >> 4) * 8;

  for (int kt = 0; kt < K; kt += 32){
    gld_lds16(A  + (size_t)(row0 + ra0) * K + kt + ka0, &Alds[c0 * 8]);
    gld_lds16(A  + (size_t)(row0 + ra1) * K + kt + ka1, &Alds[c1 * 8]);
    gld_lds16(Bw + (size_t)(col0 + ra0) * K + kt + ka0, &Blds[c0 * 8]);
    gld_lds16(Bw + (size_t)(col0 + ra1) * K + kt + ka1, &Blds[c1 * 8]);
    __syncthreads();

    short8 af[4], bf[4];
#pragma unroll
    for (int m = 0; m < 4; m++) af[m] = *(const short8*)&Alds[(wr*64 + m*16 + fr)*32 + fk8];
#pragma unroll
    for (int n = 0; n < 4; n++) bf[n] = *(const short8*)&Blds[(wc*64 + n*16 + fr)*32 + fk8];
#pragma unroll
    for (int m = 0; m < 4; m++)
#pragma unroll
      for (int n = 0; n < 4; n++)
        acc[m][n] = __builtin_amdgcn_mfma_f32_16x16x32_bf16(af[m], bf[n], acc[m][n], 0, 0, 0);
    __syncthreads();
  }

  const int rr = (lane >> 4) * 4;
#pragma unroll
  for (int n = 0; n < 4; n++){
    int col = col0 + wc*64 + n*16 + fr;
    float bv = 0.f;
    if (bias) bv = (bias2 && col >= 512) ? bias2[col - 512] : bias[col];
    if (vT && col >= 512){
      // transposed packed store: 4 consecutive rows at fixed col
#pragma unroll
      for (int m = 0; m < 4; m++){
        int row = row0 + wr*64 + m*16 + rr;
        ushort4 pk;
        pk.x = f2bf(acc[m][n][0] + bv); pk.y = f2bf(acc[m][n][1] + bv);
        pk.z = f2bf(acc[m][n][2] + bv); pk.w = f2bf(acc[m][n][3] + bv);
        *reinterpret_cast<ushort4*>(&vT[(size_t)(col - 512) * TOK + row]) = pk;
      }
    } else {
#pragma unroll
      for (int m = 0; m < 4; m++){
        int row = row0 + wr*64 + m*16 + rr;
#pragma unroll
        for (int r = 0; r < 4; r++){
          float v = acc[m][n][r] + bv;
          if (Cf) Cf[(size_t)(row + r) * ldc + col] = v;
          else    Cb[(size_t)(row + r) * ldc + col] = f2bf(v);
        }
      }
    }
  }
}

// ---------------- RoPE (in-place; q scaled by log2e/sqrt(D)) ----------------
__global__ void rope_kernel(unsigned short* __restrict__ q, unsigned short* __restrict__ k,
                            const int* __restrict__ pos,
                            const float* __restrict__ cosT, const float* __restrict__ sinT)
{
  int idx = blockIdx.x * blockDim.x + threadIdx.x;
  const int qN = TOK * NH * 64;
  if (idx < qN){
    int d  = idx & 63;
    int hh = (idx >> 6) & (NH - 1);
    int t  = idx >> 10;
    int p  = pos[t & (Ss - 1)];
    float c = cosT[p * HD + d], s = sinT[p * HD + d];
    unsigned short* base = q + (size_t)t * HIDDEN + hh * HD;
    float lo = bf2f(base[d]), hi = bf2f(base[d + 64]);
    base[d]      = f2bf((lo * c - hi * s) * QSCALE);
    base[d + 64] = f2bf((hi * c + lo * s) * QSCALE);
  } else {
    int j  = idx - qN;
    int d  = j & 63;
    int hh = (j >> 6) & (NKV - 1);
    int t  = j >> 8;
    int p  = pos[t & (Ss - 1)];
    float c = cosT[p * HD + d], s = sinT[p * HD + d];
    unsigned short* base = k + (size_t)t * KVD + hh * HD;
    float lo = bf2f(base[d]), hi = bf2f(base[d + 64]);
    base[d]      = f2bf(lo * c - hi * s);
    base[d + 64] = f2bf(hi * c + lo * s);
  }
}

// ---------------- Flash attention (GQA, 2 heads/block sharing one kv-head) ----------------
// grid: 512 blocks (qt=32, head-pair=8, batch=2), XCD-swizzled; 4 waves, wave = 16 q-rows.
__global__ __launch_bounds__(256) void attn_kernel(
    const unsigned short* __restrict__ Q,    // [TOK][HIDDEN], post-RoPE, pre-scaled
    const unsigned short* __restrict__ Kb,   // [TOK][KVD]
    const unsigned short* __restrict__ Vt,   // V^T [KVD][TOK]
    const float* __restrict__ mask,          // [Bb][Ss]
    unsigned short* __restrict__ O)          // [TOK][HIDDEN]
{
  __shared__ unsigned short Klds[64 * 136];      // K tile [64 k][128 d] padded
  __shared__ unsigned short Vlds[128 * 72];      // V^T tile [128 d][64 k] padded
  __shared__ unsigned short Plds[2][4][16 * 72]; // per-head per-wave P, XOR-swizzled

  const int bid = blockIdx.x;
  const int swz = (bid & 7) * 64 + (bid >> 3);   // XCD-contiguous work chunks
  const int qt = swz & 31, hp = (swz >> 5) & 7, b = swz >> 8;
  const int h0 = hp * 2;                         // heads h0, h0+1 share kvh
  const int kvh = hp >> 1;

  const int tid = threadIdx.x, lane = tid & 63, wid = tid >> 6;
  const int tokQ = b * Ss + qt * 64 + wid * 16;
  const int fr  = lane & 15;
  const int g16 = lane >> 4;
  const int fk8 = g16 * 8;
  const int rr  = g16 * 4;

  short8 qf[2][4];
#pragma unroll
  for (int hh = 0; hh < 2; hh++)
#pragma unroll
    for (int ks = 0; ks < 4; ks++)
      qf[hh][ks] = *(const short8*)(Q + (size_t)(tokQ + fr) * HIDDEN + (h0 + hh) * HD + ks*32 + fk8);

  const f32x4 vzero = {0.f, 0.f, 0.f, 0.f};
  f32x4 oacc[2][8];
#pragma unroll
  for (int hh = 0; hh < 2; hh++)
#pragma unroll
    for (int dn = 0; dn < 8; dn++) oacc[hh][dn] = vzero;
  float mrow[2][4], lrow[2][4];
#pragma unroll
  for (int hh = 0; hh < 2; hh++)
#pragma unroll
    for (int r = 0; r < 4; r++){ mrow[hh][r] = -1e30f; lrow[hh][r] = 0.f; }

  const float* maskrow = mask + b * Ss;
  const size_t kbase = (size_t)(b * Ss) * KVD + (size_t)kvh * HD;      // K[tok][kvh*128+d]
  const size_t vbase = (size_t)(kvh * HD) * TOK + (size_t)(b * Ss);    // V^T[kvh*128+d][tok]

  // per-thread staging geometry
  const int rK = (tid >> 4) & 63;              // c>>4 for c=tid..tid+768 step 256 -> rK + i*16
  const int dK = (tid & 15) * 8;
  const int dV = tid >> 3;                      // d for V^T chunk (c>>3): dV + i*32
  const int koV = (tid & 7) * 8;

  short8 kpre[4], vpre[4];
#pragma unroll
  for (int i = 0; i < 4; i++){
    kpre[i] = *(const short8*)(Kb + kbase + (size_t)(rK + i*16) * KVD + dK);
    vpre[i] = *(const short8*)(Vt + vbase + (size_t)(dV + i*32) * TOK + koV);
  }

  for (int kt = 0; kt < Ss / 64; kt++){
    if (kt) __syncthreads();
#pragma unroll
    for (int i = 0; i < 4; i++){
      *(short8*)&Klds[(rK + i*16) * 136 + dK] = kpre[i];
      *(short8*)&Vlds[(dV + i*32) * 72 + koV] = vpre[i];
    }
    __syncthreads();
    if (kt + 1 < Ss / 64){
      const int ks0n = (kt + 1) * 64;
#pragma unroll
      for (int i = 0; i < 4; i++){
        kpre[i] = *(const short8*)(Kb + kbase + (size_t)(ks0n + rK + i*16) * KVD + dK);
        vpre[i] = *(const short8*)(Vt + vbase + (size_t)(dV + i*32) * TOK + ks0n + koV);
      }
    }

    // S = Q K^T for both heads  [16 q-rows][64 k-cols] per wave per head
    f32x4 sf[2][4];
#pragma unroll
    for (int hh = 0; hh < 2; hh++)
#pragma unroll
      for (int n = 0; n < 4; n++) sf[hh][n] = vzero;
    __builtin_amdgcn_s_setprio(1);
#pragma unroll
    for (int ks = 0; ks < 4; ks++){
      short8 kf[4];
#pragma unroll
      for (int n = 0; n < 4; n++) kf[n] = *(const short8*)&Klds[(n*16 + fr) * 136 + ks*32 + fk8];
#pragma unroll
      for (int n = 0; n < 4; n++){
        sf[0][n] = __builtin_amdgcn_mfma_f32_16x16x32_bf16(qf[0][ks], kf[n], sf[0][n], 0, 0, 0);
        sf[1][n] = __builtin_amdgcn_mfma_f32_16x16x32_bf16(qf[1][ks], kf[n], sf[1][n], 0, 0, 0);
      }
    }
    __builtin_amdgcn_s_setprio(0);

    // mask (log2 domain), shared by both heads
    float mk[4];
#pragma unroll
    for (int n = 0; n < 4; n++) mk[n] = maskrow[kt*64 + n*16 + fr] * LOG2E;
#pragma unroll
    for (int hh = 0; hh < 2; hh++)
#pragma unroll
      for (int n = 0; n < 4; n++)
#pragma unroll
        for (int r = 0; r < 4; r++) sf[hh][n][r] += mk[n];

    // online softmax with defer-max, per head
#pragma unroll
    for (int hh = 0; hh < 2; hh++){
      float vmax[4];
#pragma unroll
      for (int r = 0; r < 4; r++){
        float vm = fmaxf(fmaxf(sf[hh][0][r], sf[hh][1][r]), fmaxf(sf[hh][2][r], sf[hh][3][r]));
#pragma unroll
        for (int off = 1; off < 16; off <<= 1) vm = fmaxf(vm, __shfl_xor(vm, off, 64));
        vmax[r] = vm;
      }
      bool need = false;
#pragma unroll
      for (int r = 0; r < 4; r++) need |= (vmax[r] > mrow[hh][r] + DEFER);
      if (__any(need)){
#pragma unroll
        for (int r = 0; r < 4; r++){
          float mnew = fmaxf(mrow[hh][r], vmax[r]);
          float sc = exp2fast(mrow[hh][r] - mnew);
          mrow[hh][r] = mnew; lrow[hh][r] *= sc;
#pragma unroll
          for (int dn = 0; dn < 8; dn++) oacc[hh][dn][r] *= sc;
        }
      }
#pragma unroll
      for (int r = 0; r < 4; r++){
        float rs = 0.f;
#pragma unroll
        for (int n = 0; n < 4; n++){
          float p = exp2fast(sf[hh][n][r] - mrow[hh][r]);
          sf[hh][n][r] = p;
          rs += p;
        }
#pragma unroll
        for (int off = 1; off < 16; off <<= 1) rs += __shfl_xor(rs, off, 64);
        lrow[hh][r] += rs;
      }
    }

    // P -> LDS (bf16, XOR-swizzled), both heads; then PV with shared V fragments
    __threadfence_block();
#pragma unroll
    for (int hh = 0; hh < 2; hh++){
      unsigned short* P = &Plds[hh][wid][0];
#pragma unroll
      for (int n = 0; n < 4; n++){
        int csw = ((n ^ g16) * 16) + fr;
#pragma unroll
        for (int r = 0; r < 4; r++)
          P[(rr + r) * 72 + csw] = f2bf(sf[hh][n][r]);
      }
    }
    __threadfence_block();

    __builtin_amdgcn_s_setprio(1);
#pragma unroll
    for (int ks2 = 0; ks2 < 2; ks2++){
      int csw = (ks2*32 + fk8) ^ (((fr >> 2) & 3) << 4);
      short8 pf0 = *(const short8*)&Plds[0][wid][fr * 72 + csw];
      short8 pf1 = *(const short8*)&Plds[1][wid][fr * 72 + csw];
#pragma unroll
      for (int dn = 0; dn < 8; dn++){
        short8 vf = *(const short8*)&Vlds[(dn*16 + fr) * 72 + ks2*32 + fk8];
        oacc[0][dn] = __builtin_amdgcn_mfma_f32_16x16x32_bf16(pf0, vf, oacc[0][dn], 0, 0, 0);
        oacc[1][dn] = __builtin_amdgcn_mfma_f32_16x16x32_bf16(pf1, vf, oacc[1][dn], 0, 0, 0);
      }
    }
    __builtin_amdgcn_s_setprio(0);
  }

  // epilogue
#pragma unroll
  for (int hh = 0; hh < 2; hh++)
#pragma unroll
    for (int r = 0; r < 4; r++){
      float inv = 1.0f / lrow[hh][r];
      int row = tokQ + rr + r;
#pragma unroll
      for (int dn = 0; dn < 8; dn++)
        O[(size_t)row * HIDDEN + (h0 + hh) * HD + dn*16 + fr] = f2bf(oacc[hh][dn][r] * inv);
    }
}

// ---------------- launcher ----------------
extern "C" void kernel_launch(void* const* d_in, const int* in_sizes, int n_in,
                              void* d_out, int out_size, void* d_ws, size_t ws_size,
                              hipStream_t stream)
{
  (void)in_sizes; (void)n_in; (void)out_size; (void)ws_size;
  const float* hs   = (const float*)d_in[0];
  const float* mask = (const float*)d_in[1];
  const int*   pos  = (const int*)d_in[2];
  const float* qw   = (const float*)d_in[3];
  const float* qb   = (const float*)d_in[4];
  const float* kw   = (const float*)d_in[5];
  const float* kb   = (const float*)d_in[6];
  const float* vw   = (const float*)d_in[7];
  const float* vb   = (const float*)d_in[8];
  const float* ow   = (const float*)d_in[9];
  const float* cosT = (const float*)d_in[10];
  const float* sinT = (const float*)d_in[11];
  float* out = (float*)d_out;

  unsigned short* ws  = (unsigned short*)d_ws;
  unsigned short* hsB = ws;                                   // [4096][2048]
  unsigned short* qwB = hsB + (size_t)TOK * HIDDEN;           // [2048][2048]
  unsigned short* kwB = qwB + (size_t)HIDDEN * HIDDEN;        // [512][2048]
  unsigned short* vwB = kwB + (size_t)KVD * HIDDEN;           // [512][2048] (contiguous with kwB)
  unsigned short* owB = vwB + (size_t)KVD * HIDDEN;           // [2048][2048]
  unsigned short* qB  = owB + (size_t)HIDDEN * HIDDEN;        // [4096][2048]
  unsigned short* kB  = qB  + (size_t)TOK * HIDDEN;           // [4096][512]
  unsigned short* vTB = kB  + (size_t)TOK * KVD;              // [512][4096]  V transposed
  unsigned short* aoB = vTB + (size_t)KVD * TOK;              // [4096][2048]
  (void)vwB;

  // one fused conversion pass (dst = ws prefix, contiguous & in order)
  cvt_all<<<R4 / 256, 256, 0, stream>>>(hs, qw, kw, vw, ow, ws);

  // projections: Q (N=2048) and combined K|V (N=1024; V half written transposed)
  gemm_nt<<<dim3(TOK/128, HIDDEN/128), 256, 0, stream>>>(hsB, qwB, qb, nullptr, qB, nullptr, nullptr, TOK, HIDDEN, HIDDEN, HIDDEN);
  gemm_nt<<<dim3(TOK/128, 1024/128),   256, 0, stream>>>(hsB, kwB, kb, vb, kB, nullptr, vTB, TOK, 1024, HIDDEN, KVD);

  // RoPE (q scaled by log2e/sqrt(D); k in [TOK][512] layout)
  {
    int total = TOK * NH * 64 + TOK * NKV * 64;
    rope_kernel<<<total / 256, 256, 0, stream>>>(qB, kB, pos, cosT, sinT);
  }

  // attention: 512 blocks, 2 heads each
  attn_kernel<<<512, 256, 0, stream>>>(qB, kB, vTB, mask, aoB);

  // output projection -> fp32 d_out
  gemm_nt<<<dim3(TOK/128, HIDDEN/128), 256, 0, stream>>>(aoB, owB, nullptr, nullptr, nullptr, out, nullptr, TOK, HIDDEN, HIDDEN, HIDDEN);
}

// Round 8
// 269.679 us; speedup vs baseline: 1.4260x; 1.4260x over previous
//
#include <hip/hip_runtime.h>

#define HIDDEN 2048
#define NH 16
#define NKV 4
#define HD 128
#define Bb 2
#define Ss 2048
#define TOK 4096           // Bb*Ss
#define KVD 512            // NKV*HD
#define LOG2E 1.4426950408889634f
#define QSCALE (0.08838834764831845f * 1.4426950408889634f)   // log2e/sqrt(128)
#define DEFER 11.54f       // 8 nats in log2 units

typedef short short8 __attribute__((ext_vector_type(8)));
typedef float f32x4 __attribute__((ext_vector_type(4)));
typedef float f32x16 __attribute__((ext_vector_type(16)));
typedef unsigned int uint4v __attribute__((ext_vector_type(4)));

#define AS1 __attribute__((address_space(1)))
#define AS3 __attribute__((address_space(3)))

__device__ __forceinline__ float exp2fast(float x){ return __builtin_amdgcn_exp2f(x); }

__device__ __forceinline__ float bf2f(unsigned short u){
  union { unsigned int i; float f; } x; x.i = ((unsigned int)u) << 16; return x.f;
}
__device__ __forceinline__ unsigned short f2bf(float f){
  union { float f; unsigned int i; } x; x.f = f;
  unsigned int r = x.i + 0x7FFFu + ((x.i >> 16) & 1u);   // RNE
  return (unsigned short)(r >> 16);
}
// pack 2 f32 -> 2 bf16 in one u32 (lo = a, hi = b), RNE
__device__ __forceinline__ unsigned int cvtpk(float a, float b){
  unsigned int r;
  asm("v_cvt_pk_bf16_f32 %0, %1, %2" : "=v"(r) : "v"(a), "v"(b));
  return r;
}
__device__ __forceinline__ void gld_lds16(const void* g, void* l){
  __builtin_amdgcn_global_load_lds((const AS1 void*)g, (AS3 void*)l, 16, 0, 0);
}

// ---------------- fused fp32 -> bf16 conversion of all 5 tensors ----------------
#define R0 2097152   // hs  f4 count
#define R1 3145728   // + qw
#define R2 3407872   // + kw
#define R3 3670016   // + vw
#define R4 4718592   // + ow (total)
__global__ void cvt_all(const float* __restrict__ s0, const float* __restrict__ s1,
                        const float* __restrict__ s2, const float* __restrict__ s3,
                        const float* __restrict__ s4, unsigned short* __restrict__ dst){
  int i = blockIdx.x * 256 + threadIdx.x;     // float4 index, grid exact
  const float* src; int off;
  if      (i < R0){ src = s0; off = 0;  }
  else if (i < R1){ src = s1; off = R0; }
  else if (i < R2){ src = s2; off = R1; }
  else if (i < R3){ src = s3; off = R2; }
  else            { src = s4; off = R3; }
  float4 v = reinterpret_cast<const float4*>(src)[i - off];
  ushort4 o;
  o.x = f2bf(v.x); o.y = f2bf(v.y); o.z = f2bf(v.z); o.w = f2bf(v.w);
  reinterpret_cast<ushort4*>(dst)[i] = o;
}

// ---------------- NT GEMM: C[M,N] = A[M,K] * B[N,K]^T (+bias) ----------------
// vT non-null: cols >= 512 are written TRANSPOSED to vT[(col-512)*TOK + row] (V^T layout).
__global__ __launch_bounds__(256) void gemm_nt(
    const unsigned short* __restrict__ A,
    const unsigned short* __restrict__ Bw,
    const float* __restrict__ bias,        // may be null
    const float* __restrict__ bias2,       // if non-null: used for col >= 512
    unsigned short* __restrict__ Cb,       // bf16 out (if Cf==null)
    float* __restrict__ Cf,                // f32 out (if non-null)
    unsigned short* __restrict__ vT,       // transposed bf16 out for col>=512
    int M, int N, int K, int ldc)
{
  __shared__ unsigned short Alds[128*32];
  __shared__ unsigned short Blds[128*32];
  const int tid  = threadIdx.x;
  const int lane = tid & 63;
  const int wr = (tid >> 7) & 1;
  const int wc = (tid >> 6) & 1;
  const int row0 = blockIdx.x * 128;
  const int col0 = blockIdx.y * 128;

  const f32x4 vzero = {0.f, 0.f, 0.f, 0.f};
  f32x4 acc[4][4];
#pragma unroll
  for (int m = 0; m < 4; m++)
#pragma unroll
    for (int n = 0; n < 4; n++) acc[m][n] = vzero;

  const int c0 = tid, c1 = tid + 256;
  const int ra0 = c0 >> 2, ka0 = (c0 & 3) * 8;
  const int ra1 = c1 >> 2, ka1 = (c1 & 3) * 8;

  const int fr  = lane & 15;
  const int fk8 = (lane >> 4) * 8;

  for (int kt = 0; kt < K; kt += 32){
    gld_lds16(A  + (size_t)(row0 + ra0) * K + kt + ka0, &Alds[c0 * 8]);
    gld_lds16(A  + (size_t)(row0 + ra1) * K + kt + ka1, &Alds[c1 * 8]);
    gld_lds16(Bw + (size_t)(col0 + ra0) * K + kt + ka0, &Blds[c0 * 8]);
    gld_lds16(Bw + (size_t)(col0 + ra1) * K + kt + ka1, &Blds[c1 * 8]);
    __syncthreads();

    short8 af[4], bf[4];
#pragma unroll
    for (int m = 0; m < 4; m++) af[m] = *(const short8*)&Alds[(wr*64 + m*16 + fr)*32 + fk8];
#pragma unroll
    for (int n = 0; n < 4; n++) bf[n] = *(const short8*)&Blds[(wc*64 + n*16 + fr)*32 + fk8];
#pragma unroll
    for (int m = 0; m < 4; m++)
#pragma unroll
      for (int n = 0; n < 4; n++)
        acc[m][n] = __builtin_amdgcn_mfma_f32_16x16x32_bf16(af[m], bf[n], acc[m][n], 0, 0, 0);
    __syncthreads();
  }

  const int rr = (lane >> 4) * 4;
#pragma unroll
  for (int n = 0; n < 4; n++){
    int col = col0 + wc*64 + n*16 + fr;
    float bv = 0.f;
    if (bias) bv = (bias2 && col >= 512) ? bias2[col - 512] : bias[col];
    if (vT && col >= 512){
      // transposed packed store: 4 consecutive rows at fixed col
#pragma unroll
      for (int m = 0; m < 4; m++){
        int row = row0 + wr*64 + m*16 + rr;
        ushort4 pk;
        pk.x = f2bf(acc[m][n][0] + bv); pk.y = f2bf(acc[m][n][1] + bv);
        pk.z = f2bf(acc[m][n][2] + bv); pk.w = f2bf(acc[m][n][3] + bv);
        *reinterpret_cast<ushort4*>(&vT[(size_t)(col - 512) * TOK + row]) = pk;
      }
    } else {
#pragma unroll
      for (int m = 0; m < 4; m++){
        int row = row0 + wr*64 + m*16 + rr;
#pragma unroll
        for (int r = 0; r < 4; r++){
          float v = acc[m][n][r] + bv;
          if (Cf) Cf[(size_t)(row + r) * ldc + col] = v;
          else    Cb[(size_t)(row + r) * ldc + col] = f2bf(v);
        }
      }
    }
  }
}

// ---------------- RoPE (in-place; q scaled by log2e/sqrt(D)) ----------------
__global__ void rope_kernel(unsigned short* __restrict__ q, unsigned short* __restrict__ k,
                            const int* __restrict__ pos,
                            const float* __restrict__ cosT, const float* __restrict__ sinT)
{
  int idx = blockIdx.x * blockDim.x + threadIdx.x;
  const int qN = TOK * NH * 64;
  if (idx < qN){
    int d  = idx & 63;
    int hh = (idx >> 6) & (NH - 1);
    int t  = idx >> 10;
    int p  = pos[t & (Ss - 1)];
    float c = cosT[p * HD + d], s = sinT[p * HD + d];
    unsigned short* base = q + (size_t)t * HIDDEN + hh * HD;
    float lo = bf2f(base[d]), hi = bf2f(base[d + 64]);
    base[d]      = f2bf((lo * c - hi * s) * QSCALE);
    base[d + 64] = f2bf((hi * c + lo * s) * QSCALE);
  } else {
    int j  = idx - qN;
    int d  = j & 63;
    int hh = (j >> 6) & (NKV - 1);
    int t  = j >> 8;
    int p  = pos[t & (Ss - 1)];
    float c = cosT[p * HD + d], s = sinT[p * HD + d];
    unsigned short* base = k + (size_t)t * KVD + hh * HD;
    float lo = bf2f(base[d]), hi = bf2f(base[d + 64]);
    base[d]      = f2bf(lo * c - hi * s);
    base[d + 64] = f2bf(hi * c + lo * s);
  }
}

// ---------------- Flash attention: swapped-QK 32x32 in-register softmax ----------------
// grid (32,4,2) = 256 blocks; 512 threads = 8 waves = 4 heads x 2 q-subtiles of 32 rows.
// Per lane: q-row = lane&31 (softmax side), h = lane>>5.
// S^T = mfma(K, Q): p[t*16+reg] = S^T[k = 32t + (reg&3)+8*(reg>>2)+4h][q = lane&31].
// PV A-frags built in-register via cvt_pk + shfl_xor(32).
__global__ __launch_bounds__(512, 2) void attn_kernel(
    const unsigned short* __restrict__ Q,    // [TOK][HIDDEN], post-RoPE, pre-scaled
    const unsigned short* __restrict__ Kb,   // [TOK][KVD]
    const unsigned short* __restrict__ Vt,   // V^T [KVD][TOK]
    const float* __restrict__ mask,          // [Bb][Ss]
    unsigned short* __restrict__ O)          // [TOK][HIDDEN]
{
  __shared__ unsigned short Klds[64*128];    // [k][d], XOR-swizzled (e ^= (k&7)<<3)
  __shared__ unsigned short Vlds[128*64];    // V^T [d][k], XOR-swizzled (e ^= (d&7)<<3)

  const int tid = threadIdx.x, lane = tid & 63, wid = tid >> 6;
  const int qt = blockIdx.x, kvh = blockIdx.y, b = blockIdx.z;
  const int head = kvh*4 + (wid >> 1);
  const int q0 = lane & 31;          // this lane's q-row (softmax) / d-col (PV out)
  const int h  = lane >> 5;          // half-wave id
  const int tokQ = b*Ss + qt*64 + (wid & 1)*32;

  // Q fragments in registers: 8 d-slots of 16 (B-frag: col=q0, k-elems h*8..h*8+7)
  short8 qf[8];
#pragma unroll
  for (int ds = 0; ds < 8; ds++)
    qf[ds] = *(const short8*)(Q + (size_t)(tokQ + q0)*HIDDEN + head*HD + ds*16 + h*8);

  f32x16 oacc[4];
#pragma unroll
  for (int dblk = 0; dblk < 4; dblk++)
#pragma unroll
    for (int r = 0; r < 16; r++) oacc[dblk][r] = 0.f;
  float mrow = -1e30f, lrow = 0.f;

  const float* maskrow = mask + b*Ss;

  // staging geometry (per thread, 2 rounds each of K and V^T)
  const int kk0 = tid >> 4;          // K row 0..31 (+32 second round)
  const int kd  = tid & 15;          // K 16B slice
  const int dv0 = tid >> 3;          // V^T row 0..63 (+64 second round)
  const int vk  = tid & 7;           // V^T 16B slice

  const size_t kgbase = (size_t)(b*Ss)*KVD + (size_t)kvh*HD;
  const size_t vgbase = (size_t)(kvh*HD)*TOK + (size_t)(b*Ss);

  short8 kpre[2], vpre[2];
#pragma unroll
  for (int i = 0; i < 2; i++){
    kpre[i] = *(const short8*)(Kb + kgbase + (size_t)(kk0 + i*32)*KVD + kd*8);
    vpre[i] = *(const short8*)(Vt + vgbase + (size_t)(dv0 + i*64)*TOK + vk*8);
  }

  for (int kt = 0; kt < Ss/64; kt++){
    if (kt) __syncthreads();
    // write prefetched tile to LDS (swizzled)
#pragma unroll
    for (int i = 0; i < 2; i++){
      int kk = kk0 + i*32;
      *(short8*)&Klds[kk*128 + ((kd*8) ^ ((kk & 7) << 3))] = kpre[i];
      int dv = dv0 + i*64;
      *(short8*)&Vlds[dv*64 + ((vk*8) ^ ((dv & 7) << 3))] = vpre[i];
    }
    __syncthreads();
    // prefetch next tile (hides under compute)
    if (kt + 1 < Ss/64){
      const int tok = (kt + 1)*64;
#pragma unroll
      for (int i = 0; i < 2; i++){
        kpre[i] = *(const short8*)(Kb + kgbase + (size_t)(tok + kk0 + i*32)*KVD + kd*8);
        vpre[i] = *(const short8*)(Vt + vgbase + (size_t)(dv0 + i*64)*TOK + tok + vk*8);
      }
    }

    // ---- S^T = K * Q^T : two 32x32 outputs (k-tiles t=0,1), chained over 8 d-slots
    f32x16 st0, st1;
#pragma unroll
    for (int r = 0; r < 16; r++){ st0[r] = 0.f; st1[r] = 0.f; }
    __builtin_amdgcn_s_setprio(1);
#pragma unroll
    for (int ds = 0; ds < 8; ds++){
      short8 kf0 = *(const short8*)&Klds[(q0     )*128 + ((ds*16 + h*8) ^ ((q0 & 7) << 3))];
      short8 kf1 = *(const short8*)&Klds[(32 + q0)*128 + ((ds*16 + h*8) ^ ((q0 & 7) << 3))];
      st0 = __builtin_amdgcn_mfma_f32_32x32x16_bf16(kf0, qf[ds], st0, 0, 0, 0);
      st1 = __builtin_amdgcn_mfma_f32_32x32x16_bf16(kf1, qf[ds], st1, 0, 0, 0);
    }
    __builtin_amdgcn_s_setprio(0);

    // ---- mask add (log2 domain); p[t*16+reg], k = 32t + (reg&3)+8*(reg>>2)+4h
    float p[32];
#pragma unroll
    for (int g2 = 0; g2 < 4; g2++){
      f32x4 m0 = *(const f32x4*)(maskrow + kt*64      + g2*8 + h*4);
      f32x4 m1 = *(const f32x4*)(maskrow + kt*64 + 32 + g2*8 + h*4);
#pragma unroll
      for (int r = 0; r < 4; r++){
        p[g2*4 + r]      = st0[g2*4 + r] + m0[r] * LOG2E;
        p[16 + g2*4 + r] = st1[g2*4 + r] + m1[r] * LOG2E;
      }
    }

    // ---- online softmax (in-register; row is lane-local, 1 cross-lane op)
    float vmax = p[0];
#pragma unroll
    for (int i = 1; i < 32; i++) vmax = fmaxf(vmax, p[i]);
    vmax = fmaxf(vmax, __shfl_xor(vmax, 32));
    if (__any(vmax > mrow + DEFER)){
      float mnew = fmaxf(mrow, vmax);
      float sc = exp2fast(mrow - mnew);
      mrow = mnew; lrow *= sc;
#pragma unroll
      for (int reg = 0; reg < 16; reg++){
        float scr = __shfl(sc, (reg & 3) + 8*(reg >> 2) + 4*h);
#pragma unroll
        for (int dblk = 0; dblk < 4; dblk++) oacc[dblk][reg] *= scr;
      }
    }
    float rs = 0.f;
#pragma unroll
    for (int i = 0; i < 32; i++){ p[i] = exp2fast(p[i] - mrow); rs += p[i]; }
    rs += __shfl_xor(rs, 32);
    lrow += rs;

    // ---- pack P to bf16 and build PV A-frags via one shfl_xor(32) exchange
    unsigned int pk[8][2];
#pragma unroll
    for (int G = 0; G < 8; G++){
      pk[G][0] = cvtpk(p[G*4 + 0], p[G*4 + 1]);
      pk[G][1] = cvtpk(p[G*4 + 2], p[G*4 + 3]);
    }
    short8 pa[4];
#pragma unroll
    for (int ks = 0; ks < 4; ks++){
      const int ia = 4*(ks >> 1) + 2*(ks & 1);
      unsigned int A0 = pk[ia][0],   A1 = pk[ia][1];
      unsigned int B0 = pk[ia+1][0], B1 = pk[ia+1][1];
      unsigned int s0 = h ? A0 : B0, s1 = h ? A1 : B1;
      unsigned int r0 = (unsigned int)__shfl_xor((int)s0, 32);
      unsigned int r1 = (unsigned int)__shfl_xor((int)s1, 32);
      uint4v w = { h ? r0 : A0, h ? r1 : A1, h ? B0 : r0, h ? B1 : r1 };
      pa[ks] = __builtin_bit_cast(short8, w);
    }

    // ---- O += P * V  (A = pa[ks], B = V^T fragments from LDS)
    __builtin_amdgcn_s_setprio(1);
#pragma unroll
    for (int dblk = 0; dblk < 4; dblk++){
#pragma unroll
      for (int ks = 0; ks < 4; ks++){
        short8 vb = *(const short8*)&Vlds[(dblk*32 + q0)*64 + ((ks*16 + h*8) ^ ((q0 & 7) << 3))];
        oacc[dblk] = __builtin_amdgcn_mfma_f32_32x32x16_bf16(pa[ks], vb, oacc[dblk], 0, 0, 0);
      }
    }
    __builtin_amdgcn_s_setprio(0);
  }

  // ---- epilogue: O[q = crow(reg,h)][d = dblk*32 + q0]
  float inv = 1.0f / lrow;
#pragma unroll
  for (int reg = 0; reg < 16; reg++){
    const int crow = (reg & 3) + 8*(reg >> 2) + 4*h;
    float invr = __shfl(inv, crow);
    int row = tokQ + crow;
#pragma unroll
    for (int dblk = 0; dblk < 4; dblk++)
      O[(size_t)row*HIDDEN + head*HD + dblk*32 + q0] = f2bf(oacc[dblk][reg] * invr);
  }
}

// ---------------- launcher ----------------
extern "C" void kernel_launch(void* const* d_in, const int* in_sizes, int n_in,
                              void* d_out, int out_size, void* d_ws, size_t ws_size,
                              hipStream_t stream)
{
  (void)in_sizes; (void)n_in; (void)out_size; (void)ws_size;
  const float* hs   = (const float*)d_in[0];
  const float* mask = (const float*)d_in[1];
  const int*   pos  = (const int*)d_in[2];
  const float* qw   = (const float*)d_in[3];
  const float* qb   = (const float*)d_in[4];
  const float* kw   = (const float*)d_in[5];
  const float* kb   = (const float*)d_in[6];
  const float* vw   = (const float*)d_in[7];
  const float* vb   = (const float*)d_in[8];
  const float* ow   = (const float*)d_in[9];
  const float* cosT = (const float*)d_in[10];
  const float* sinT = (const float*)d_in[11];
  float* out = (float*)d_out;

  unsigned short* ws  = (unsigned short*)d_ws;
  unsigned short* hsB = ws;                                   // [4096][2048]
  unsigned short* qwB = hsB + (size_t)TOK * HIDDEN;           // [2048][2048]
  unsigned short* kwB = qwB + (size_t)HIDDEN * HIDDEN;        // [512][2048]
  unsigned short* vwB = kwB + (size_t)KVD * HIDDEN;           // [512][2048] (contiguous with kwB)
  unsigned short* owB = vwB + (size_t)KVD * HIDDEN;           // [2048][2048]
  unsigned short* qB  = owB + (size_t)HIDDEN * HIDDEN;        // [4096][2048]
  unsigned short* kB  = qB  + (size_t)TOK * HIDDEN;           // [4096][512]
  unsigned short* vTB = kB  + (size_t)TOK * KVD;              // [512][4096]  V transposed
  unsigned short* aoB = vTB + (size_t)KVD * TOK;              // [4096][2048]
  (void)vwB;

  // one fused conversion pass (dst = ws prefix, contiguous & in order)
  cvt_all<<<R4 / 256, 256, 0, stream>>>(hs, qw, kw, vw, ow, ws);

  // projections: Q (N=2048) and combined K|V (N=1024; V half written transposed)
  gemm_nt<<<dim3(TOK/128, HIDDEN/128), 256, 0, stream>>>(hsB, qwB, qb, nullptr, qB, nullptr, nullptr, TOK, HIDDEN, HIDDEN, HIDDEN);
  gemm_nt<<<dim3(TOK/128, 1024/128),   256, 0, stream>>>(hsB, kwB, kb, vb, kB, nullptr, vTB, TOK, 1024, HIDDEN, KVD);

  // RoPE (q scaled by log2e/sqrt(D); k in [TOK][512] layout)
  {
    int total = TOK * NH * 64 + TOK * NKV * 64;
    rope_kernel<<<total / 256, 256, 0, stream>>>(qB, kB, pos, cosT, sinT);
  }

  // attention: 256 blocks x 512 threads (8 waves = 4 heads x 2 q-subtiles)
  attn_kernel<<<dim3(Ss/64, NKV, Bb), 512, 0, stream>>>(qB, kB, vTB, mask, aoB);

  // output projection -> fp32 d_out
  gemm_nt<<<dim3(TOK/128, HIDDEN/128), 256, 0, stream>>>(aoB, owB, nullptr, nullptr, nullptr, out, nullptr, TOK, HIDDEN, HIDDEN, HIDDEN);
}

// Round 9
// 223.768 us; speedup vs baseline: 1.7186x; 1.2052x over previous
//
#include <hip/hip_runtime.h>

#define HIDDEN 2048
#define NH 16
#define NKV 4
#define HD 128
#define Bb 2
#define Ss 2048
#define TOK 4096           // Bb*Ss
#define KVD 512            // NKV*HD
#define LOG2E 1.4426950408889634f
#define QSCALE (0.08838834764831845f * 1.4426950408889634f)   // log2e/sqrt(128)
#define DEFER 11.54f       // 8 nats in log2 units

typedef short short8 __attribute__((ext_vector_type(8)));
typedef float f32x4 __attribute__((ext_vector_type(4)));
typedef float f32x16 __attribute__((ext_vector_type(16)));
typedef unsigned int uint4v __attribute__((ext_vector_type(4)));

#define AS1 __attribute__((address_space(1)))
#define AS3 __attribute__((address_space(3)))

#define BARRIER() asm volatile("s_barrier" ::: "memory")
#define WAITV8()  asm volatile("s_waitcnt vmcnt(8)" ::: "memory")
#define WAITV0()  asm volatile("s_waitcnt vmcnt(0)" ::: "memory")

__device__ __forceinline__ float exp2fast(float x){ return __builtin_amdgcn_exp2f(x); }

__device__ __forceinline__ float bf2f(unsigned short u){
  union { unsigned int i; float f; } x; x.i = ((unsigned int)u) << 16; return x.f;
}
__device__ __forceinline__ unsigned short f2bf(float f){
  union { float f; unsigned int i; } x; x.f = f;
  unsigned int r = x.i + 0x7FFFu + ((x.i >> 16) & 1u);   // RNE
  return (unsigned short)(r >> 16);
}
// pack 2 f32 -> 2 bf16 in one u32 (lo = a, hi = b), RNE
__device__ __forceinline__ unsigned int cvtpk(float a, float b){
  unsigned int r;
  asm("v_cvt_pk_bf16_f32 %0, %1, %2" : "=v"(r) : "v"(a), "v"(b));
  return r;
}
__device__ __forceinline__ void gld_lds16(const void* g, void* l){
  __builtin_amdgcn_global_load_lds((const AS1 void*)g, (AS3 void*)l, 16, 0, 0);
}

// ---------------- fused fp32 -> bf16 conversion of all 5 tensors ----------------
#define R0 2097152   // hs  f4 count
#define R1 3145728   // + qw
#define R2 3407872   // + kw
#define R3 3670016   // + vw
#define R4 4718592   // + ow (total)
__global__ void cvt_all(const float* __restrict__ s0, const float* __restrict__ s1,
                        const float* __restrict__ s2, const float* __restrict__ s3,
                        const float* __restrict__ s4, unsigned short* __restrict__ dst){
  int i = blockIdx.x * 256 + threadIdx.x;     // float4 index, grid exact
  const float* src; int off;
  if      (i < R0){ src = s0; off = 0;  }
  else if (i < R1){ src = s1; off = R0; }
  else if (i < R2){ src = s2; off = R1; }
  else if (i < R3){ src = s3; off = R2; }
  else            { src = s4; off = R3; }
  float4 v = reinterpret_cast<const float4*>(src)[i - off];
  ushort4 o;
  o.x = f2bf(v.x); o.y = f2bf(v.y); o.z = f2bf(v.z); o.w = f2bf(v.w);
  reinterpret_cast<ushort4*>(dst)[i] = o;
}

// ---------------- NT GEMM: C[M,N] = A[M,K] * B[N,K]^T (+bias) ----------------
// 128x128 tile, BK=64, double-buffered LDS with counted vmcnt (T3/T4),
// XOR-swizzled LDS (slot ^= row&7; inverse-swizzled global src per rule #21).
// vT non-null: cols >= 512 are written TRANSPOSED to vT[(col-512)*TOK + row].
__global__ __launch_bounds__(256, 2) void gemm_nt(
    const unsigned short* __restrict__ A,
    const unsigned short* __restrict__ Bw,
    const float* __restrict__ bias,        // may be null
    const float* __restrict__ bias2,       // if non-null: used for col >= 512
    unsigned short* __restrict__ Cb,       // bf16 out (if Cf==null)
    float* __restrict__ Cf,                // f32 out (if non-null)
    unsigned short* __restrict__ vT,       // transposed bf16 out for col>=512
    int M, int N, int K, int ldc)
{
  __shared__ unsigned short lds[2][2][128*64];   // [buf][A|B][row*64 + elem]
  const int tid  = threadIdx.x;
  const int lane = tid & 63;
  const int w  = tid >> 6;          // wave 0..3
  const int wr = w >> 1, wc = w & 1;
  const int row0 = blockIdx.x * 128;
  const int col0 = blockIdx.y * 128;
  const int fr  = lane & 15;
  const int g16 = lane >> 4;
  const int l8  = lane >> 3;        // staging sub-row 0..7
  const int slot = lane & 7;        // staging 16B slot 0..7

  const f32x4 vzero = {0.f, 0.f, 0.f, 0.f};
  f32x4 acc[4][4];
#pragma unroll
  for (int m = 0; m < 4; m++)
#pragma unroll
    for (int n = 0; n < 4; n++) acc[m][n] = vzero;

  // stage one 128x64 K-tile of A and B into lds[buf] (8 gload_lds/thread)
  auto STAGE = [&](int buf, int kt){
#pragma unroll
    for (int i = 0; i < 4; i++){
      int r = w*32 + i*8 + l8;
      gld_lds16(A  + (size_t)(row0 + r)*K + kt*64 + ((slot ^ (r & 7)) << 3),
                &lds[buf][0][w*2048 + i*512 + lane*8]);
    }
#pragma unroll
    for (int i = 0; i < 4; i++){
      int r = w*32 + i*8 + l8;
      gld_lds16(Bw + (size_t)(col0 + r)*K + kt*64 + ((slot ^ (r & 7)) << 3),
                &lds[buf][1][w*2048 + i*512 + lane*8]);
    }
  };

  const int NT = K >> 6;
  STAGE(0, 0);
  STAGE(1, 1);
  WAITV8();            // tile 0 landed (tile 1 still in flight)
  BARRIER();

  for (int kt = 0; kt < NT; kt++){
    const int cur = kt & 1;
    const unsigned short* Al = &lds[cur][0][0];
    const unsigned short* Bl = &lds[cur][1][0];
#pragma unroll
    for (int ks = 0; ks < 2; ks++){
      short8 af[4], bf[4];
#pragma unroll
      for (int m = 0; m < 4; m++){
        int r = wr*64 + m*16 + fr;
        af[m] = *(const short8*)&Al[r*64 + (((ks*4 + g16) ^ (r & 7)) << 3)];
      }
#pragma unroll
      for (int n = 0; n < 4; n++){
        int r = wc*64 + n*16 + fr;
        bf[n] = *(const short8*)&Bl[r*64 + (((ks*4 + g16) ^ (r & 7)) << 3)];
      }
      __builtin_amdgcn_s_setprio(1);
#pragma unroll
      for (int m = 0; m < 4; m++)
#pragma unroll
        for (int n = 0; n < 4; n++)
          acc[m][n] = __builtin_amdgcn_mfma_f32_16x16x32_bf16(af[m], bf[n], acc[m][n], 0, 0, 0);
      __builtin_amdgcn_s_setprio(0);
    }
    if (kt == NT - 1) break;
    BARRIER();                       // all waves done reading lds[cur]
    if (kt + 2 < NT){
      STAGE(cur, kt + 2);            // refill the buffer just consumed
      WAITV8();                      // tile kt+1's 8 loads complete (kt+2's stay in flight)
    } else {
      WAITV0();                      // last tile's loads complete
    }
    BARRIER();                       // writes visible to all waves
  }

  const int rr = g16 * 4;
#pragma unroll
  for (int n = 0; n < 4; n++){
    int col = col0 + wc*64 + n*16 + fr;
    float bv = 0.f;
    if (bias) bv = (bias2 && col >= 512) ? bias2[col - 512] : bias[col];
    if (vT && col >= 512){
      // transposed packed store: 4 consecutive rows at fixed col
#pragma unroll
      for (int m = 0; m < 4; m++){
        int row = row0 + wr*64 + m*16 + rr;
        ushort4 pk;
        pk.x = f2bf(acc[m][n][0] + bv); pk.y = f2bf(acc[m][n][1] + bv);
        pk.z = f2bf(acc[m][n][2] + bv); pk.w = f2bf(acc[m][n][3] + bv);
        *reinterpret_cast<ushort4*>(&vT[(size_t)(col - 512) * TOK + row]) = pk;
      }
    } else {
#pragma unroll
      for (int m = 0; m < 4; m++){
        int row = row0 + wr*64 + m*16 + rr;
#pragma unroll
        for (int r = 0; r < 4; r++){
          float v = acc[m][n][r] + bv;
          if (Cf) Cf[(size_t)(row + r) * ldc + col] = v;
          else    Cb[(size_t)(row + r) * ldc + col] = f2bf(v);
        }
      }
    }
  }
}

// ---------------- RoPE (in-place; q scaled by log2e/sqrt(D)) ----------------
__global__ void rope_kernel(unsigned short* __restrict__ q, unsigned short* __restrict__ k,
                            const int* __restrict__ pos,
                            const float* __restrict__ cosT, const float* __restrict__ sinT)
{
  int idx = blockIdx.x * blockDim.x + threadIdx.x;
  const int qN = TOK * NH * 64;
  if (idx < qN){
    int d  = idx & 63;
    int hh = (idx >> 6) & (NH - 1);
    int t  = idx >> 10;
    int p  = pos[t & (Ss - 1)];
    float c = cosT[p * HD + d], s = sinT[p * HD + d];
    unsigned short* base = q + (size_t)t * HIDDEN + hh * HD;
    float lo = bf2f(base[d]), hi = bf2f(base[d + 64]);
    base[d]      = f2bf((lo * c - hi * s) * QSCALE);
    base[d + 64] = f2bf((hi * c + lo * s) * QSCALE);
  } else {
    int j  = idx - qN;
    int d  = j & 63;
    int hh = (j >> 6) & (NKV - 1);
    int t  = j >> 8;
    int p  = pos[t & (Ss - 1)];
    float c = cosT[p * HD + d], s = sinT[p * HD + d];
    unsigned short* base = k + (size_t)t * KVD + hh * HD;
    float lo = bf2f(base[d]), hi = bf2f(base[d + 64]);
    base[d]      = f2bf(lo * c - hi * s);
    base[d + 64] = f2bf(hi * c + lo * s);
  }
}

// ---------------- Flash attention: swapped-QK 32x32 in-register softmax ----------------
// grid (32,4,2) = 256 blocks; 512 threads = 8 waves = 4 heads x 2 q-subtiles of 32 rows.
__global__ __launch_bounds__(512, 2) void attn_kernel(
    const unsigned short* __restrict__ Q,    // [TOK][HIDDEN], post-RoPE, pre-scaled
    const unsigned short* __restrict__ Kb,   // [TOK][KVD]
    const unsigned short* __restrict__ Vt,   // V^T [KVD][TOK]
    const float* __restrict__ mask,          // [Bb][Ss]
    unsigned short* __restrict__ O)          // [TOK][HIDDEN]
{
  __shared__ unsigned short Klds[64*128];    // [k][d], XOR-swizzled (e ^= (k&7)<<3)
  __shared__ unsigned short Vlds[128*64];    // V^T [d][k], XOR-swizzled (e ^= (d&7)<<3)

  const int tid = threadIdx.x, lane = tid & 63, wid = tid >> 6;
  const int qt = blockIdx.x, kvh = blockIdx.y, b = blockIdx.z;
  const int head = kvh*4 + (wid >> 1);
  const int q0 = lane & 31;          // this lane's q-row (softmax) / d-col (PV out)
  const int h  = lane >> 5;          // half-wave id
  const int tokQ = b*Ss + qt*64 + (wid & 1)*32;

  // Q fragments in registers: 8 d-slots of 16 (B-frag: col=q0, k-elems h*8..h*8+7)
  short8 qf[8];
#pragma unroll
  for (int ds = 0; ds < 8; ds++)
    qf[ds] = *(const short8*)(Q + (size_t)(tokQ + q0)*HIDDEN + head*HD + ds*16 + h*8);

  f32x16 oacc[4];
#pragma unroll
  for (int dblk = 0; dblk < 4; dblk++)
#pragma unroll
    for (int r = 0; r < 16; r++) oacc[dblk][r] = 0.f;
  float mrow = -1e30f, lrow = 0.f;

  const float* maskrow = mask + b*Ss;

  // staging geometry (per thread, 2 rounds each of K and V^T)
  const int kk0 = tid >> 4;          // K row 0..31 (+32 second round)
  const int kd  = tid & 15;          // K 16B slice
  const int dv0 = tid >> 3;          // V^T row 0..63 (+64 second round)
  const int vk  = tid & 7;           // V^T 16B slice

  const size_t kgbase = (size_t)(b*Ss)*KVD + (size_t)kvh*HD;
  const size_t vgbase = (size_t)(kvh*HD)*TOK + (size_t)(b*Ss);

  short8 kpre[2], vpre[2];
#pragma unroll
  for (int i = 0; i < 2; i++){
    kpre[i] = *(const short8*)(Kb + kgbase + (size_t)(kk0 + i*32)*KVD + kd*8);
    vpre[i] = *(const short8*)(Vt + vgbase + (size_t)(dv0 + i*64)*TOK + vk*8);
  }

  for (int kt = 0; kt < Ss/64; kt++){
    if (kt) __syncthreads();
    // write prefetched tile to LDS (swizzled)
#pragma unroll
    for (int i = 0; i < 2; i++){
      int kk = kk0 + i*32;
      *(short8*)&Klds[kk*128 + ((kd*8) ^ ((kk & 7) << 3))] = kpre[i];
      int dv = dv0 + i*64;
      *(short8*)&Vlds[dv*64 + ((vk*8) ^ ((dv & 7) << 3))] = vpre[i];
    }
    __syncthreads();
    // prefetch next tile (hides under compute)
    if (kt + 1 < Ss/64){
      const int tok = (kt + 1)*64;
#pragma unroll
      for (int i = 0; i < 2; i++){
        kpre[i] = *(const short8*)(Kb + kgbase + (size_t)(tok + kk0 + i*32)*KVD + kd*8);
        vpre[i] = *(const short8*)(Vt + vgbase + (size_t)(dv0 + i*64)*TOK + tok + vk*8);
      }
    }

    // ---- S^T = K * Q^T : two 32x32 outputs (k-tiles t=0,1), chained over 8 d-slots
    f32x16 st0, st1;
#pragma unroll
    for (int r = 0; r < 16; r++){ st0[r] = 0.f; st1[r] = 0.f; }
    __builtin_amdgcn_s_setprio(1);
#pragma unroll
    for (int ds = 0; ds < 8; ds++){
      short8 kf0 = *(const short8*)&Klds[(q0     )*128 + ((ds*16 + h*8) ^ ((q0 & 7) << 3))];
      short8 kf1 = *(const short8*)&Klds[(32 + q0)*128 + ((ds*16 + h*8) ^ ((q0 & 7) << 3))];
      st0 = __builtin_amdgcn_mfma_f32_32x32x16_bf16(kf0, qf[ds], st0, 0, 0, 0);
      st1 = __builtin_amdgcn_mfma_f32_32x32x16_bf16(kf1, qf[ds], st1, 0, 0, 0);
    }
    __builtin_amdgcn_s_setprio(0);

    // ---- mask add (log2 domain); p[t*16+reg], k = 32t + (reg&3)+8*(reg>>2)+4h
    float p[32];
#pragma unroll
    for (int g2 = 0; g2 < 4; g2++){
      f32x4 m0 = *(const f32x4*)(maskrow + kt*64      + g2*8 + h*4);
      f32x4 m1 = *(const f32x4*)(maskrow + kt*64 + 32 + g2*8 + h*4);
#pragma unroll
      for (int r = 0; r < 4; r++){
        p[g2*4 + r]      = st0[g2*4 + r] + m0[r] * LOG2E;
        p[16 + g2*4 + r] = st1[g2*4 + r] + m1[r] * LOG2E;
      }
    }

    // ---- online softmax (in-register; row is lane-local, 1 cross-lane op)
    float vmax = p[0];
#pragma unroll
    for (int i = 1; i < 32; i++) vmax = fmaxf(vmax, p[i]);
    vmax = fmaxf(vmax, __shfl_xor(vmax, 32));
    if (__any(vmax > mrow + DEFER)){
      float mnew = fmaxf(mrow, vmax);
      float sc = exp2fast(mrow - mnew);
      mrow = mnew; lrow *= sc;
#pragma unroll
      for (int reg = 0; reg < 16; reg++){
        float scr = __shfl(sc, (reg & 3) + 8*(reg >> 2) + 4*h);
#pragma unroll
        for (int dblk = 0; dblk < 4; dblk++) oacc[dblk][reg] *= scr;
      }
    }
    float rs = 0.f;
#pragma unroll
    for (int i = 0; i < 32; i++){ p[i] = exp2fast(p[i] - mrow); rs += p[i]; }
    rs += __shfl_xor(rs, 32);
    lrow += rs;

    // ---- pack P to bf16 and build PV A-frags via one shfl_xor(32) exchange
    unsigned int pk[8][2];
#pragma unroll
    for (int G = 0; G < 8; G++){
      pk[G][0] = cvtpk(p[G*4 + 0], p[G*4 + 1]);
      pk[G][1] = cvtpk(p[G*4 + 2], p[G*4 + 3]);
    }
    short8 pa[4];
#pragma unroll
    for (int ks = 0; ks < 4; ks++){
      const int ia = 4*(ks >> 1) + 2*(ks & 1);
      unsigned int A0 = pk[ia][0],   A1 = pk[ia][1];
      unsigned int B0 = pk[ia+1][0], B1 = pk[ia+1][1];
      unsigned int s0 = h ? A0 : B0, s1 = h ? A1 : B1;
      unsigned int r0 = (unsigned int)__shfl_xor((int)s0, 32);
      unsigned int r1 = (unsigned int)__shfl_xor((int)s1, 32);
      uint4v w = { h ? r0 : A0, h ? r1 : A1, h ? B0 : r0, h ? B1 : r1 };
      pa[ks] = __builtin_bit_cast(short8, w);
    }

    // ---- O += P * V  (A = pa[ks], B = V^T fragments from LDS)
    __builtin_amdgcn_s_setprio(1);
#pragma unroll
    for (int dblk = 0; dblk < 4; dblk++){
#pragma unroll
      for (int ks = 0; ks < 4; ks++){
        short8 vb = *(const short8*)&Vlds[(dblk*32 + q0)*64 + ((ks*16 + h*8) ^ ((q0 & 7) << 3))];
        oacc[dblk] = __builtin_amdgcn_mfma_f32_32x32x16_bf16(pa[ks], vb, oacc[dblk], 0, 0, 0);
      }
    }
    __builtin_amdgcn_s_setprio(0);
  }

  // ---- epilogue: O[q = crow(reg,h)][d = dblk*32 + q0]
  float inv = 1.0f / lrow;
#pragma unroll
  for (int reg = 0; reg < 16; reg++){
    const int crow = (reg & 3) + 8*(reg >> 2) + 4*h;
    float invr = __shfl(inv, crow);
    int row = tokQ + crow;
#pragma unroll
    for (int dblk = 0; dblk < 4; dblk++)
      O[(size_t)row*HIDDEN + head*HD + dblk*32 + q0] = f2bf(oacc[dblk][reg] * invr);
  }
}

// ---------------- launcher ----------------
extern "C" void kernel_launch(void* const* d_in, const int* in_sizes, int n_in,
                              void* d_out, int out_size, void* d_ws, size_t ws_size,
                              hipStream_t stream)
{
  (void)in_sizes; (void)n_in; (void)out_size; (void)ws_size;
  const float* hs   = (const float*)d_in[0];
  const float* mask = (const float*)d_in[1];
  const int*   pos  = (const int*)d_in[2];
  const float* qw   = (const float*)d_in[3];
  const float* qb   = (const float*)d_in[4];
  const float* kw   = (const float*)d_in[5];
  const float* kb   = (const float*)d_in[6];
  const float* vw   = (const float*)d_in[7];
  const float* vb   = (const float*)d_in[8];
  const float* ow   = (const float*)d_in[9];
  const float* cosT = (const float*)d_in[10];
  const float* sinT = (const float*)d_in[11];
  float* out = (float*)d_out;

  unsigned short* ws  = (unsigned short*)d_ws;
  unsigned short* hsB = ws;                                   // [4096][2048]
  unsigned short* qwB = hsB + (size_t)TOK * HIDDEN;           // [2048][2048]
  unsigned short* kwB = qwB + (size_t)HIDDEN * HIDDEN;        // [512][2048]
  unsigned short* vwB = kwB + (size_t)KVD * HIDDEN;           // [512][2048] (contiguous with kwB)
  unsigned short* owB = vwB + (size_t)KVD * HIDDEN;           // [2048][2048]
  unsigned short* qB  = owB + (size_t)HIDDEN * HIDDEN;        // [4096][2048]
  unsigned short* kB  = qB  + (size_t)TOK * HIDDEN;           // [4096][512]
  unsigned short* vTB = kB  + (size_t)TOK * KVD;              // [512][4096]  V transposed
  unsigned short* aoB = vTB + (size_t)KVD * TOK;              // [4096][2048]
  (void)vwB;

  // one fused conversion pass (dst = ws prefix, contiguous & in order)
  cvt_all<<<R4 / 256, 256, 0, stream>>>(hs, qw, kw, vw, ow, ws);

  // projections: Q (N=2048) and combined K|V (N=1024; V half written transposed)
  gemm_nt<<<dim3(TOK/128, HIDDEN/128), 256, 0, stream>>>(hsB, qwB, qb, nullptr, qB, nullptr, nullptr, TOK, HIDDEN, HIDDEN, HIDDEN);
  gemm_nt<<<dim3(TOK/128, 1024/128),   256, 0, stream>>>(hsB, kwB, kb, vb, kB, nullptr, vTB, TOK, 1024, HIDDEN, KVD);

  // RoPE (q scaled by log2e/sqrt(D); k in [TOK][512] layout)
  {
    int total = TOK * NH * 64 + TOK * NKV * 64;
    rope_kernel<<<total / 256, 256, 0, stream>>>(qB, kB, pos, cosT, sinT);
  }

  // attention: 256 blocks x 512 threads (8 waves = 4 heads x 2 q-subtiles)
  attn_kernel<<<dim3(Ss/64, NKV, Bb), 512, 0, stream>>>(qB, kB, vTB, mask, aoB);

  // output projection -> fp32 d_out
  gemm_nt<<<dim3(TOK/128, HIDDEN/128), 256, 0, stream>>>(aoB, owB, nullptr, nullptr, nullptr, out, nullptr, TOK, HIDDEN, HIDDEN, HIDDEN);
}